// Round 10
// baseline (79.104 us; speedup 1.0000x reference)
//
#include <hip/hip_runtime.h>
#include <stdint.h>

// DSVDD fused: dist = sqrt(||phi||^2 + ||c||^2 - 2 phi.c), top-3 smallest, softmin score.
// bf16 MFMA computes S = phi.c - ||c||^2/2 (centers folded into K-pad 112->128),
// track top-3 LARGEST S per row == 3 smallest distances.
// R10: DEEP-PREFETCH whole-chunk LDS staging. R6..R9 all had ~1-tile prefetch depth and
// all landed at 57-66us: af load latency (~L3, since phi streaming thrashes CT2 out of
// the 4MB per-XCD L2) exposed every tile. Now: 512-thr blocks (8 waves, 256 rows),
// 128KB LDS = two 4-tile windows; ALL chunk DMAs issued up front; monotone counted
// vmcnt(8)->vmcnt(4)->vmcnt(0) (AITER pattern), 4 barriers/block, depth = 4 tiles.

typedef short s16x8 __attribute__((ext_vector_type(8)));
typedef float fx4 __attribute__((ext_vector_type(4)));

#define M_TOT 3136
#define CC 112
#define NROWS 50176
#define NT 10       // tiles per chunk (S=5 chunks x 10 tiles x 64 m = 3200)
#define S_CHUNKS 5

__device__ __forceinline__ unsigned short f2bf(float x) {
  unsigned u = __float_as_uint(x);
  u += 0x7fffu + ((u >> 16) & 1u);  // RNE
  return (unsigned short)(u >> 16);
}

__device__ __forceinline__ void async16(const void* g, void* l) {
  __builtin_amdgcn_global_load_lds(
      (const __attribute__((address_space(1))) unsigned int*)g,
      (__attribute__((address_space(3))) unsigned int*)l, 16, 0, 0);
}

// insert v into descending triple (t0 >= t1 >= t2), keep 3 largest. 3 VALU ops.
#define INSERT3(T0, T1, T2, V)                                  \
  do {                                                          \
    const float _a0 = (T0), _a1 = (T1), _v = (V);               \
    (T0) = fmaxf(_a0, _v);                                      \
    (T1) = __builtin_amdgcn_fmed3f(_a0, _a1, _v);               \
    (T2) = __builtin_amdgcn_fmed3f(_a1, (T2), _v);              \
  } while (0)

// ---- prep0: fold value per padded m: -||c_m||^2/8, sentinel -2500 for m>=M_TOT ----
__global__ __launch_bounds__(256) void dsvdd_prep0(const float* __restrict__ Cb,
                                                   float* __restrict__ foldv) {
  const int m = blockIdx.x * 256 + threadIdx.x;
  if (m >= 3200) return;
  float r = -2500.0f;
  if (m < M_TOT) {
    float ss = 0.f;
    for (int k = 0; k < CC; ++k) {
      const float x = Cb[(size_t)k * M_TOT + m];
      ss += x * x;
    }
    r = -0.125f * ss;
  }
  foldv[m] = r;
}

// ---- prep1: CT2[tile][f][ks][lane] 16B slots, fragment-ordered for MFMA A-operand ----
// slot value: 8 bf16 = CT[m = tile*64+f*16+(lane&15)][k = ks*32+(lane>>4)*8 + 0..7]
// where CT[m][k] = C_bank[k][m] (k<112); foldv[m] (112<=k<116); 0 else.
__global__ __launch_bounds__(256) void dsvdd_prep1(const float* __restrict__ Cb,
                                                   const float* __restrict__ foldv,
                                                   unsigned char* __restrict__ CT2) {
  const int tile = blockIdx.x >> 2;
  const int s = (blockIdx.x & 3) * 256 + threadIdx.x;  // 0..1023 slot of tile
  const int f = s >> 8;
  const int ks = (s >> 6) & 3;
  const int l = s & 63;
  const int mm = tile * 64 + f * 16 + (l & 15);
  const bool mv = (mm < M_TOT);
  const int k0 = ks * 32 + (l >> 4) * 8;
  const float fv = foldv[mm];
  float v[8];
#pragma unroll
  for (int j = 0; j < 8; ++j) {
    const int k = k0 + j;
    float x = 0.f;
    if (k < CC) x = mv ? Cb[(size_t)k * M_TOT + mm] : 0.f;
    else if (k < 116) x = fv;
    v[j] = x;
  }
  uint4 pk;
  pk.x = (unsigned)f2bf(v[0]) | ((unsigned)f2bf(v[1]) << 16);
  pk.y = (unsigned)f2bf(v[2]) | ((unsigned)f2bf(v[3]) << 16);
  pk.z = (unsigned)f2bf(v[4]) | ((unsigned)f2bf(v[5]) << 16);
  pk.w = (unsigned)f2bf(v[6]) | ((unsigned)f2bf(v[7]) << 16);
  *(uint4*)(CT2 + (size_t)tile * 16384 + (size_t)s * 16) = pk;
}

// ---- stage1: block = 256 rows x one 640-m chunk (10 tiles). 8 waves = 4 rg x 2 mh. ----
__global__ __launch_bounds__(512, 2) void dsvdd_stage1(const float* __restrict__ phi,
                                                       const unsigned char* __restrict__ CT2,
                                                       float* __restrict__ part,
                                                       float* __restrict__ featg) {
  __shared__ __align__(16) unsigned char lds[131072];  // A: tiles 0-3 (then 8-9), B: 4-7
  float(*const mg)[8] = (float(*)[8])lds;              // epilogue alias, 256x8 f32

  const int t = threadIdx.x;
  const int lane = t & 63;
  const int w = t >> 6;   // 0..7
  const int g = w >> 1;   // row-group: rows [g*64, g*64+64)
  const int h = w & 1;    // m-half: fragments f = h*2, h*2+1
  const int cq = lane & 15;
  const int kq = lane >> 4;
  const int c = blockIdx.y;
  const size_t chunkB = (size_t)c * (NT * 16384);
  const long rowBase = (long)blockIdx.x * 256;
  const bool needF = (c == 0);

  // ---- phi -> bg fragments direct-to-reg (64 rows/wave) + features (c==0, h==0) ----
  s16x8 bg[4][4];  // [ks][pf]
  float ssr[4];
#pragma unroll
  for (int pf = 0; pf < 4; ++pf) {
    ssr[pf] = 0.f;
    const float* rp = phi + (size_t)(rowBase + g * 64 + pf * 16 + cq) * CC;
#pragma unroll
    for (int ks = 0; ks < 4; ++ks) {
      const int k0 = ks * 32 + kq * 8;
      s16x8 v;
      if (k0 <= 104) {
        const float4 a = *(const float4*)(rp + k0);
        const float4 b = *(const float4*)(rp + k0 + 4);
        if (needF) {
          ssr[pf] += a.x * a.x + a.y * a.y + a.z * a.z + a.w * a.w;
          ssr[pf] += b.x * b.x + b.y * b.y + b.z * b.z + b.w * b.w;
        }
        v[0] = (short)f2bf(a.x); v[1] = (short)f2bf(a.y);
        v[2] = (short)f2bf(a.z); v[3] = (short)f2bf(a.w);
        v[4] = (short)f2bf(b.x); v[5] = (short)f2bf(b.y);
        v[6] = (short)f2bf(b.z); v[7] = (short)f2bf(b.w);
      } else if (k0 == 112) {  // fold slots: four 1.0, four 0
        v[0] = v[1] = v[2] = v[3] = (short)0x3f80;
        v[4] = v[5] = v[6] = v[7] = 0;
      } else {
        v = (s16x8)0;
      }
      bg[ks][pf] = v;
    }
    if (needF) {
      ssr[pf] += __shfl_xor(ssr[pf], 16);
      ssr[pf] += __shfl_xor(ssr[pf], 32);
    }
  }
  if (needF && h == 0 && kq == 0) {
#pragma unroll
    for (int pf = 0; pf < 4; ++pf)
      featg[rowBase + g * 64 + pf * 16 + cq] = ssr[pf];
  }

  float t0[4], t1[4], t2[4];
#pragma unroll
  for (int pf = 0; pf < 4; ++pf) t0[pf] = t1[pf] = t2[pf] = -3.0e38f;

// issue a DMA window: NI instrs/wave, wave-sliced; LDS dest uniform base + lane*16
#define ISSUE(LDSOFF, CHOFF, PERW, NI)                                          \
  do {                                                                          \
    const unsigned char* _g = CT2 + chunkB + (CHOFF) + w * (PERW) + (size_t)lane * 16; \
    unsigned char* _l = lds + (LDSOFF) + w * (PERW);                            \
    _Pragma("unroll") for (int i = 0; i < (NI); ++i)                            \
        async16(_g + i * 1024, _l + i * 1024);                                  \
  } while (0)

#define COMPUTE(RD)                                                             \
  do {                                                                          \
    const unsigned char* _rd = (RD);                                            \
    const fx4 _zz = {0.f, 0.f, 0.f, 0.f};                                       \
    _Pragma("unroll") for (int mf = 0; mf < 2; ++mf) {                          \
      s16x8 af[4];                                                              \
      _Pragma("unroll") for (int ks = 0; ks < 4; ++ks)                          \
          af[ks] = *(const s16x8*)(_rd + ((h * 2 + mf) * 4 + ks) * 1024 +       \
                                   lane * 16);                                  \
      fx4 acc[4];                                                               \
      _Pragma("unroll") for (int ks = 0; ks < 4; ++ks)                          \
          _Pragma("unroll") for (int pf = 0; pf < 4; ++pf)                      \
              acc[pf] = __builtin_amdgcn_mfma_f32_16x16x32_bf16(                \
                  af[ks], bg[ks][pf], (ks == 0) ? _zz : acc[pf], 0, 0, 0);      \
      _Pragma("unroll") for (int pf = 0; pf < 4; ++pf)                          \
          _Pragma("unroll") for (int rg = 0; rg < 4; ++rg)                      \
              INSERT3(t0[pf], t1[pf], t2[pf], acc[pf][rg]);                     \
    }                                                                           \
  } while (0)

#define FENCE() __builtin_amdgcn_sched_barrier(0)

  // issue both 4-tile windows up front (16 DMAs/wave in flight)
  ISSUE(0, 0, 8192, 8);           // w0: tiles 0-3 -> A
  ISSUE(65536, 65536, 8192, 8);   // w1: tiles 4-7 -> B
  FENCE();
  asm volatile("s_waitcnt vmcnt(8)" ::: "memory");  // own w0 done
  FENCE();
  __builtin_amdgcn_s_barrier();                     // all waves' w0 done
  FENCE();
  COMPUTE(lds + 0 * 16384);
  COMPUTE(lds + 1 * 16384);
  COMPUTE(lds + 2 * 16384);
  COMPUTE(lds + 3 * 16384);
  FENCE();
  __builtin_amdgcn_s_barrier();                     // all waves done reading A
  FENCE();
  ISSUE(0, 131072, 4096, 4);      // w2: tiles 8-9 -> A[0..32K)
  FENCE();
  asm volatile("s_waitcnt vmcnt(4)" ::: "memory");  // own w1 done (w2 may be in flight)
  FENCE();
  __builtin_amdgcn_s_barrier();                     // all waves' w1 done
  FENCE();
  COMPUTE(lds + 65536 + 0 * 16384);
  COMPUTE(lds + 65536 + 1 * 16384);
  COMPUTE(lds + 65536 + 2 * 16384);
  COMPUTE(lds + 65536 + 3 * 16384);
  FENCE();
  asm volatile("s_waitcnt vmcnt(0)" ::: "memory");  // own w2 done
  FENCE();
  __builtin_amdgcn_s_barrier();                     // all waves' w2 done
  FENCE();
  COMPUTE(lds + 0 * 16384);
  COMPUTE(lds + 1 * 16384);

#undef ISSUE
#undef COMPUTE
#undef FENCE

  // ---- merge the 4 kq groups within each wave ----
#pragma unroll
  for (int pf = 0; pf < 4; ++pf) {
#pragma unroll
    for (int off = 16; off < 64; off <<= 1) {
      const float b0 = __shfl_xor(t0[pf], off);
      const float b1 = __shfl_xor(t1[pf], off);
      const float b2 = __shfl_xor(t2[pf], off);
      INSERT3(t0[pf], t1[pf], t2[pf], b0);
      INSERT3(t0[pf], t1[pf], t2[pf], b1);
      INSERT3(t0[pf], t1[pf], t2[pf], b2);
    }
  }
  __syncthreads();  // all tile reads done; safe to alias mg onto lds
  if (kq == 0) {
#pragma unroll
    for (int pf = 0; pf < 4; ++pf) {
      const int row = g * 64 + pf * 16 + cq;
      mg[row][h * 3 + 0] = t0[pf];
      mg[row][h * 3 + 1] = t1[pf];
      mg[row][h * 3 + 2] = t2[pf];
    }
  }
  __syncthreads();
  if (t < 256) {
    float s0 = mg[t][0], s1 = mg[t][1], s2 = mg[t][2];
    INSERT3(s0, s1, s2, mg[t][3]);
    INSERT3(s0, s1, s2, mg[t][4]);
    INSERT3(s0, s1, s2, mg[t][5]);
    float* dst = part + ((size_t)c * NROWS + rowBase + t) * 3;
    dst[0] = s0; dst[1] = s1; dst[2] = s2;
  }
}

// ---- stage2: merge S partial triples per row, sqrt + softmin, write score ----
__global__ __launch_bounds__(256) void dsvdd_stage2(const float* __restrict__ part,
                                                    const float* __restrict__ featg,
                                                    float* __restrict__ out) {
  const int row = blockIdx.x * 256 + threadIdx.x;
  if (row >= NROWS) return;
  float s0 = -3.0e38f, s1 = -3.0e38f, s2 = -3.0e38f;
#pragma unroll
  for (int c = 0; c < S_CHUNKS; ++c) {
    const float* p = part + ((size_t)c * NROWS + row) * 3;
    INSERT3(s0, s1, s2, p[0]);
    INSERT3(s0, s1, s2, p[1]);
    INSERT3(s0, s1, s2, p[2]);
  }
  const float feat = featg[row];
  const float d0 = sqrtf(fmaxf(feat - 2.f * s0, 0.f));
  const float d1 = sqrtf(fmaxf(feat - 2.f * s1, 0.f));
  const float d2 = sqrtf(fmaxf(feat - 2.f * s2, 0.f));
  const float w0 = 1.0f / (1.0f + __expf(d0 - d1) + __expf(d0 - d2));
  out[row] = w0 * d0;
}

extern "C" void kernel_launch(void* const* d_in, const int* in_sizes, int n_in,
                              void* d_out, int out_size, void* d_ws, size_t ws_size,
                              hipStream_t stream) {
  (void)in_sizes; (void)n_in; (void)out_size; (void)ws_size;
  const float* phi = (const float*)d_in[0];
  const float* Cb = (const float*)d_in[1];
  float* out = (float*)d_out;
  unsigned char* CT2 = (unsigned char*)d_ws;               // 819200 B
  float* foldv = (float*)((unsigned char*)d_ws + 819200);  // 12800 B
  float* featg = (float*)((unsigned char*)d_ws + 832000);  // 200704 B
  float* partp = (float*)((unsigned char*)d_ws + 1032704); // 5*50176*12 = 3010560 B
  dsvdd_prep0<<<13, 256, 0, stream>>>(Cb, foldv);
  dsvdd_prep1<<<200, 256, 0, stream>>>(Cb, foldv, CT2);
  dsvdd_stage1<<<dim3(196, S_CHUNKS), 512, 0, stream>>>(phi, CT2, partp, featg);
  dsvdd_stage2<<<196, 256, 0, stream>>>(partp, featg, out);
}